// Round 10
// baseline (182.846 us; speedup 1.0000x reference)
//
#include <hip/hip_runtime.h>
#include <stdint.h>

typedef unsigned short u16;
typedef __attribute__((ext_vector_type(8))) short bf16x8;   // 8 bf16 = 4 VGPRs (MFMA A/B frag)
typedef __attribute__((ext_vector_type(4))) float f32x4;    // MFMA C/D frag
typedef __attribute__((ext_vector_type(16))) float f32x16;  // MFMA C/D frag (32x32)
typedef __attribute__((ext_vector_type(4))) unsigned int u32x4;
typedef __attribute__((ext_vector_type(2))) unsigned int u32x2;
typedef __attribute__((ext_vector_type(4))) unsigned short u16x4;

#define QSCALE 0.18033688011112042f   // 0.125 * log2(e): softmax scale folded into Q, exp via exp2

typedef __attribute__((address_space(1))) const void gvoid;
typedef __attribute__((address_space(3))) void svoid;

__device__ __forceinline__ void cp16(const u16* g, u16* l) {
    // async global->LDS, 16B/lane; LDS dst = wave-uniform base + lane*16
    __builtin_amdgcn_global_load_lds((gvoid*)g, (svoid*)l, 16, 0, 0);
}

__device__ __forceinline__ u16 f2bf(float f) {
    uint32_t u = __float_as_uint(f);
    u += 0x7fff + ((u >> 16) & 1);   // round-to-nearest-even
    return (u16)(u >> 16);
}

// pack bf16(lo), bf16(hi) into one u32 via the HW packer (T12, RTNE) — 1 op per 2 elems
__device__ __forceinline__ uint32_t cvtpk_bf2(float lo, float hi) {
    uint32_t r;
    asm("v_cvt_pk_bf16_f32 %0, %1, %2" : "=v"(r) : "v"(lo), "v"(hi));
    return r;
}

__device__ __forceinline__ f32x16 zero16() {
    f32x16 v;
    #pragma unroll
    for (int i = 0; i < 16; i++) v[i] = 0.f;
    return v;
}

// ---------------------------------------------------------------- fused pre-pass:
// blocks [0,4096): LayerNorm token t -> XN bf16; blocks [4096,8192): weight fp32->bf16 cast
__global__ __launch_bounds__(256) void k_pre(const float* __restrict__ X,
                                             const float* __restrict__ gam,
                                             const float* __restrict__ bet,
                                             u16* __restrict__ XN,
                                             const float* __restrict__ Wqkv, u16* __restrict__ Wq,
                                             const float* __restrict__ Wout, u16* __restrict__ Wo) {
    __shared__ float red[8];
    const int bid = blockIdx.x;
    if (bid < 4096) {
        int t = bid;
        const float4* xp = (const float4*)(X + (size_t)t * 1024);
        float4 x = xp[threadIdx.x];
        float s  = x.x + x.y + x.z + x.w;
        float s2 = x.x*x.x + x.y*x.y + x.z*x.z + x.w*x.w;
        #pragma unroll
        for (int off = 1; off < 64; off <<= 1) {
            s  += __shfl_xor(s,  off, 64);
            s2 += __shfl_xor(s2, off, 64);
        }
        int lane = threadIdx.x & 63, w = threadIdx.x >> 6;
        if (lane == 0) { red[w] = s; red[w + 4] = s2; }
        __syncthreads();
        s  = red[0] + red[1] + red[2] + red[3];
        s2 = red[4] + red[5] + red[6] + red[7];
        float mu  = s * (1.0f / 1024.0f);
        float var = s2 * (1.0f / 1024.0f) - mu * mu;
        float rin = rsqrtf(var + 1e-5f);
        float4 g = ((const float4*)gam)[threadIdx.x];
        float4 b = ((const float4*)bet)[threadIdx.x];
        u16x4 o;
        o.x = f2bf((x.x - mu) * rin * g.x + b.x);
        o.y = f2bf((x.y - mu) * rin * g.y + b.y);
        o.z = f2bf((x.z - mu) * rin * g.z + b.z);
        o.w = f2bf((x.w - mu) * rin * g.w + b.w);
        *(u16x4*)(XN + (size_t)t * 1024 + threadIdx.x * 4) = o;
    } else {
        int i = (bid - 4096) * 256 + threadIdx.x;      // over 1048576 float4s total
        const float* src; u16* dst;
        if (i < 786432) { src = Wqkv; dst = Wq; }
        else            { i -= 786432; src = Wout; dst = Wo; }
        float4 v = ((const float4*)src)[i];
        u16x4 o;
        o.x = f2bf(v.x); o.y = f2bf(v.y); o.z = f2bf(v.z); o.w = f2bf(v.w);
        ((u16x4*)dst)[i] = o;
    }
}

// ---------------------------------------------------------------- QKV GEMM: 256x256 tile, 8-phase
// T2(swizzle)+T3(8-phase)+T4(counted vmcnt, never 0 in steady state)+T5(setprio) per the verified
// 256^2 template. BK=64, 8 waves (2M x 4N), per-wave 128x64 output, acc[8][4] f32x4.

#define CFENCE asm volatile("" ::: "memory")
#define BARX() do { CFENCE; __builtin_amdgcn_s_barrier(); CFENCE; } while (0)
#define LGKM0() asm volatile("s_waitcnt lgkmcnt(0)" ::: "memory")

__global__ __launch_bounds__(512, 2) void k_qkv(const u16* __restrict__ XN, const u16* __restrict__ Wq,
                                                const float* __restrict__ bqkv,
                                                u16* __restrict__ Q, u16* __restrict__ K,
                                                u16* __restrict__ Vt) {
    __shared__ __align__(16) u16 SMEM[65536];      // 128 KiB; reused for V-transpose in epilogue
    const int tid = threadIdx.x;
    const int lane = tid & 63, w = tid >> 6;       // w in 0..7
    const int qi = lane & 15, g = lane >> 4, swz = qi & 7;
    const int wr = (w >> 2) * 128, wc = (w & 3) * 64;

    // bijective XCD swizzle: 192 blocks, 24/XCD -> each XCD owns 2 contiguous M-rows (A-panel L2 reuse)
    const int id = blockIdx.x;
    const int sw = (id & 7) * 24 + (id >> 3);
    const int n0 = (sw % 12) * 256;
    const int m0 = (sw / 12) * 256;

    // staging thread constants (all stage-region base rows are multiples of 8 -> same swizzle const)
    const int laneRow = lane >> 3, laneCg = lane & 7;
    const int cs = laneCg ^ laneRow;
    const int aw = (w & 3) * 8 + (w >> 2) * 128;   // A-chunk wave base row (add q*32)
    const u16* gA = XN + (size_t)(m0 + aw + laneRow) * 1024 + cs * 8;
    const u16* gB = Wq + (size_t)(n0 + w * 8 + laneRow) * 1024 + cs * 8;

#define SM_A(s) (SMEM + (s) * 32768)
#define SM_B(s) (SMEM + (s) * 32768 + 16384)
#define STAGE_A(tau, q, s) cp16(gA + (size_t)(q) * 32 * 1024 + (tau) * 64, SM_A(s) + ((q) * 32 + aw) * 64)
#define STAGE_B(tau, part, s)                                                                       \
    do { cp16(gB + (size_t)(part) * 128 * 1024 + (tau) * 64, SM_B(s) + ((part) * 128 + w * 8) * 64); \
         cp16(gB + (size_t)((part) * 128 + 64) * 1024 + (tau) * 64,                                  \
              SM_B(s) + ((part) * 128 + 64 + w * 8) * 64); } while (0)

    f32x4 acc[8][4];
    #pragma unroll
    for (int mi = 0; mi < 8; mi++)
        #pragma unroll
        for (int ni = 0; ni < 4; ni++) acc[mi][ni] = (f32x4){0.f, 0.f, 0.f, 0.f};
    bf16x8 bf[4][2];

    // prologue: tile0 fully (8 loads) + tile1 minus Aq2/Aq3 (6 loads); wait 8 oldest
    STAGE_B(0, 0, 0); STAGE_B(0, 1, 0);
    STAGE_A(0, 0, 0); STAGE_A(0, 1, 0); STAGE_A(0, 2, 0); STAGE_A(0, 3, 0);
    STAGE_B(1, 0, 1); STAGE_B(1, 1, 1);
    STAGE_A(1, 0, 1); STAGE_A(1, 1, 1);
    asm volatile("s_waitcnt vmcnt(6)" ::: "memory");
    BARX();

#define PHASE_A(q)                                                                                   \
    bf16x8 af[2][2];                                                                                 \
    _Pragma("unroll") for (int m2 = 0; m2 < 2; m2++)                                                 \
    _Pragma("unroll") for (int ks = 0; ks < 2; ks++)                                                 \
        af[m2][ks] = *(const bf16x8*)(as_ + (wr + ((q) * 2 + m2) * 16 + qi) * 64 + (((ks * 4 + g) ^ swz)) * 8);

#define DO_MFMA(q)                                                                                   \
    __builtin_amdgcn_s_setprio(1);                                                                   \
    _Pragma("unroll") for (int m2 = 0; m2 < 2; m2++)                                                 \
    _Pragma("unroll") for (int ni = 0; ni < 4; ni++) {                                               \
        acc[(q) * 2 + m2][ni] = __builtin_amdgcn_mfma_f32_16x16x32_bf16(af[m2][0], bf[ni][0], acc[(q) * 2 + m2][ni], 0, 0, 0); \
        acc[(q) * 2 + m2][ni] = __builtin_amdgcn_mfma_f32_16x16x32_bf16(af[m2][1], bf[ni][1], acc[(q) * 2 + m2][ni], 0, 0, 0); \
    }                                                                                                \
    __builtin_amdgcn_s_setprio(0);

    for (int t = 0; t < 16; t++) {
        const int s = t & 1;
        const u16* as_ = SM_A(s);
        const u16* bs_ = SM_B(s);
        {   // phase 0: B-frags (held all tile) + A quadrant 0
            PHASE_A(0)
            #pragma unroll
            for (int ni = 0; ni < 4; ni++)
                #pragma unroll
                for (int ks = 0; ks < 2; ks++)
                    bf[ni][ks] = *(const bf16x8*)(bs_ + (wc + ni * 16 + qi) * 64 + ((ks * 4 + g) ^ swz) * 8);
            if (t < 15) { STAGE_A(t + 1, 2, s ^ 1); STAGE_A(t + 1, 3, s ^ 1); }
            BARX(); LGKM0();
            DO_MFMA(0)
            BARX();
        }
        {   // phase 1
            PHASE_A(1)
            if (t < 14) STAGE_B(t + 2, 0, s);
            BARX(); LGKM0();
            DO_MFMA(1)
            BARX();
        }
        {   // phase 2
            PHASE_A(2)
            if (t < 14) STAGE_B(t + 2, 1, s);
            BARX(); LGKM0();
            DO_MFMA(2)
            BARX();
        }
        {   // phase 3: boundary wait — counted vmcnt, drain only at tail
            PHASE_A(3)
            if (t < 14) { STAGE_A(t + 2, 0, s); STAGE_A(t + 2, 1, s); }
            BARX(); LGKM0();
            DO_MFMA(3)
            if (t < 14) { asm volatile("s_waitcnt vmcnt(6)" ::: "memory"); }
            else        { asm volatile("s_waitcnt vmcnt(0)" ::: "memory"); }
            BARX();
        }
    }

    // ---- epilogue (final BARX above separates last LDS reads from reuse)
    if (n0 < 2048) {
        const int which = n0 >> 10;                // 0 = Q, 1 = K (block-uniform; 256-tiles don't straddle)
        u16* base = which ? K : Q;
        const float scale = which ? 1.0f : QSCALE;
        #pragma unroll
        for (int mi = 0; mi < 8; mi++)
            #pragma unroll
            for (int ni = 0; ni < 4; ni++)
                #pragma unroll
                for (int i = 0; i < 4; i++) {
                    int m = m0 + wr + mi * 16 + (g * 4 + i);
                    int n = n0 + wc + ni * 16 + qi;
                    float v = (acc[mi][ni][i] + bqkv[n]) * scale;
                    int b = m >> 11, ss = m & 2047;
                    int hh = (n >> 6) & 15, d = n & 63;
                    base[((size_t)(b * 16 + hh) * 2048 + ss) * 64 + d] = f2bf(v);
                }
    } else {
        u16* Tw = SMEM + w * 4352;                 // per-wave 64x68 (stride 68: 8B-aligned rows)
        const int head = (n0 + wc - 2048) >> 6;    // each wave owns exactly one head's 64 dims
        const int b = m0 >> 11;
        #pragma unroll
        for (int h = 0; h < 2; h++) {              // two 64-row m-halves of the wave's 128 rows
            #pragma unroll
            for (int mi2 = 0; mi2 < 4; mi2++)
                #pragma unroll
                for (int ni = 0; ni < 4; ni++) {
                    int mi = h * 4 + mi2;
                    int n = n0 + wc + ni * 16 + qi;
                    float bq = bqkv[n];
                    u16x4 pk;
                    pk.x = f2bf(acc[mi][ni][0] + bq);
                    pk.y = f2bf(acc[mi][ni][1] + bq);
                    pk.z = f2bf(acc[mi][ni][2] + bq);
                    pk.w = f2bf(acc[mi][ni][3] + bq);
                    *(u16x4*)(Tw + (ni * 16 + qi) * 68 + mi2 * 16 + g * 4) = pk;
                }
            int s0 = (m0 + wr + h * 64) & 2047;    // s within the batch
            u16* vrow = Vt + (size_t)(b * 16 + head) * 64 * 2048 + s0 + qi * 4;
            #pragma unroll
            for (int dd = 0; dd < 16; dd++) {
                int d = dd * 4 + g;
                u16x4 val = *(const u16x4*)(Tw + d * 68 + qi * 4);
                *(u16x4*)(vrow + (size_t)d * 2048) = val;
            }
        }
    }
#undef SM_A
#undef SM_B
#undef STAGE_A
#undef STAGE_B
#undef PHASE_A
#undef DO_MFMA
}

// ---------------------------------------------------------------- attention — R25: split-K 32x32 in the R23 geometry
// R23 is DS-issue-bound (16 b128/wave/step x 16 waves x ~12cy ~= wall). The 32x32 family halves
// DS per q but both prior attempts used degraded geometry (R19: 8 waves/CU; R21: 4-wave blocks,
// 2.4 blocks/CU resident). R25 = split-K 32x32 inside R23's PROVEN geometry: 512 blocks x 8 waves
// (2 blocks/CU, 16 waves/CU), q-tile 128. Wave (qg = w>>1, kh = w&1): 32 q x 32-key half.
// Per wave-step: 4 K-frag + 4 V-frag b128 reads (8 total, was 16), 8 MFMA 32x32x16, 16 exp2.
// P in-register via permlane32_swap (R19/R21 HW-verified); cvt_pk (R22); staging = R23's exact
// 1 K + 1 V cp16/wave. End: split-K combine via dedicated CB buffer (R21-verified pattern).
// LDS 65.5 KB -> still 2 blocks/CU.
__global__ __launch_bounds__(512) void k_attn(const u16* __restrict__ Q, const u16* __restrict__ K,
                                              const u16* __restrict__ Vt, u16* __restrict__ CTX) {
    __shared__ __align__(16) u16 Ks[2][64 * 64];   // elem(key r, d c) at r*64 + ((c>>3)^(r&7))*8 + (c&7)
    __shared__ __align__(16) u16 Vs[2][64 * 64];   // elem(d r, key c) same swizzle
    __shared__ __align__(16) float CB[4][2048];    // od combine: qg x (64 lanes x 32 floats, XOR-chunked)
    __shared__ float CBl[4][64];                   // lsum combine
    const int id = blockIdx.x;
    const int bh = (id & 7) * 4 + ((id >> 3) & 3); // id%8 constant per bh -> same XCD
    const int q0 = (id >> 5) * 128;
    const int lane = threadIdx.x & 63, w = threadIdx.x >> 6;   // w in 0..7
    const int l = lane & 31, h = lane >> 5;
    const int qg = w >> 1, kh = w & 1;             // q-group (4 x 32q), key-half (2 x 32k)
    const u16* Qp = Q  + (size_t)bh * (2048 * 64);
    const u16* Kp = K  + (size_t)bh * (2048 * 64);
    const u16* Vp = Vt + (size_t)bh * (64 * 2048);

    // staging (R23-exact): 8 waves x 64 lanes x 16B = one full 64x64 bf16 tile per cp16
    const int r0 = w * 8 + (lane >> 3);            // tile row 0..63
    const int cs = (lane & 7) ^ (r0 & 7);          // swizzled col-granule
    const u16* kg = Kp + (size_t)r0 * 64 + cs * 8;
    const u16* vg = Vp + (size_t)r0 * 2048 + cs * 8;

    // Q in registers: bq[dk] = Q[q][dk*16 + 8h .. +7], q = q0 + qg*32 + l   (R19/R21 verified)
    bf16x8 bq[4];
    {
        const u16* qb = Qp + (size_t)(q0 + qg * 32 + l) * 64 + h * 8;
        #pragma unroll
        for (int dk = 0; dk < 4; dk++) bq[dk] = *(const bf16x8*)(qb + dk * 16);
    }
    float ls = 0.f;
    f32x16 od0 = zero16(), od1 = zero16();

    // preload tile 0 -> buf 0
    cp16(kg, Ks[0] + w * 512);
    cp16(vg, Vs[0] + w * 512);

    for (int t = 0; t < 32; ++t) {
        __syncthreads();                           // drains vmcnt: K(t),V(t) landed
        if (t < 31) {
            cp16(kg + 4096, Ks[(t + 1) & 1] + w * 512);
            cp16(vg + 64,   Vs[(t + 1) & 1] + w * 512);
        }
        kg += 4096; vg += 64;
        const u16* ksp = Ks[t & 1];
        const u16* vsp = Vs[t & 1];

        // QK^T over this wave's 32-key half: sv[reg] = score(key = kh*32 + (reg&3)+8*(reg>>2)+4h, q)
        f32x16 sv = zero16();
        __builtin_amdgcn_s_setprio(1);
        #pragma unroll
        for (int dk = 0; dk < 4; dk++) {
            bf16x8 ak = *(const bf16x8*)(ksp + (kh * 32 + l) * 64 + ((2 * dk + h) ^ (l & 7)) * 8);
            sv = __builtin_amdgcn_mfma_f32_32x32x16_bf16(ak, bq[dk], sv, 0, 0, 0);
        }
        __builtin_amdgcn_s_setprio(0);

        // softmax-exp + cvt_pk: y[p][s] = bf16 pair of keys kh*32 + 8s+4h+2p .. +1
        uint32_t y[2][4];
        #pragma unroll
        for (int s = 0; s < 4; s++)
            #pragma unroll
            for (int p = 0; p < 2; p++) {
                float e0 = __builtin_amdgcn_exp2f(sv[4 * s + 2 * p]);
                float e1 = __builtin_amdgcn_exp2f(sv[4 * s + 2 * p + 1]);
                ls += e0 + e1;
                y[p][s] = cvtpk_bf2(e0, e1);
            }

        // PV over the 32-key half: 2 k-mfmas x 2 d-groups; B-frag via 2 permlane32_swap (R21-verified)
        #pragma unroll
        for (int mt = 0; mt < 2; mt++) {
            u32x2 r0s = __builtin_amdgcn_permlane32_swap(y[0][2 * mt], y[0][2 * mt + 1], false, false);
            u32x2 r1s = __builtin_amdgcn_permlane32_swap(y[1][2 * mt], y[1][2 * mt + 1], false, false);
            u32x4 bw = {r0s.x, r1s.x, r0s.y, r1s.y};   // slots 0..3
            bf16x8 bp = *(const bf16x8*)&bw;
            bf16x8 av0 = *(const bf16x8*)(vsp + (l) * 64      + ((kh * 4 + 2 * mt + h) ^ (l & 7)) * 8);
            bf16x8 av1 = *(const bf16x8*)(vsp + (32 + l) * 64 + ((kh * 4 + 2 * mt + h) ^ (l & 7)) * 8);
            __builtin_amdgcn_s_setprio(1);
            od0 = __builtin_amdgcn_mfma_f32_32x32x16_bf16(av0, bp, od0, 0, 0, 0);
            od1 = __builtin_amdgcn_mfma_f32_32x32x16_bf16(av1, bp, od1, 0, 0, 0);
            __builtin_amdgcn_s_setprio(0);
        }
    }

    // ---- split-K combine (R21-verified pattern, dedicated CB buffer): kh=1 -> LDS -> kh=0 finishes
    float* cb = &CB[0][0];
    __syncthreads();
    if (kh == 1) {
        #pragma unroll
        for (int c = 0; c < 8; c++) {              // chunk c: od0 regs 4c.. (c<4) else od1
            f32x4 v;
            if (c < 4) { v.x = od0[4*c+0]; v.y = od0[4*c+1]; v.z = od0[4*c+2]; v.w = od0[4*c+3]; }
            else       { v.x = od1[4*(c-4)+0]; v.y = od1[4*(c-4)+1]; v.z = od1[4*(c-4)+2]; v.w = od1[4*(c-4)+3]; }
            *(f32x4*)(cb + qg * 2048 + lane * 32 + (c ^ (lane & 7)) * 4) = v;
        }
        CBl[qg][lane] = ls;
    }
    __syncthreads();
    if (kh == 0) {
        #pragma unroll
        for (int c = 0; c < 8; c++) {
            f32x4 v = *(const f32x4*)(cb + qg * 2048 + lane * 32 + (c ^ (lane & 7)) * 4);
            if (c < 4) { od0[4*c+0] += v.x; od0[4*c+1] += v.y; od0[4*c+2] += v.z; od0[4*c+3] += v.w; }
            else       { od1[4*(c-4)+0] += v.x; od1[4*(c-4)+1] += v.y; od1[4*(c-4)+2] += v.z; od1[4*(c-4)+3] += v.w; }
        }
        ls += CBl[qg][lane];
        float lsum = ls + __shfl_xor(ls, 32, 64);  // lanes (l,0)/(l,32): complementary h-subsets
        float inv = 1.0f / lsum;
        const int b = bh >> 4, hh = bh & 15;
        size_t m = (size_t)b * 2048 + q0 + qg * 32 + l;
        u16* cp = CTX + m * 1024 + hh * 64;
        #pragma unroll
        for (int s = 0; s < 4; s++) {              // d = dg*32 + 8s + 4h + {0..3}
            u16x4 o;
            o.x = f2bf(od0[4 * s + 0] * inv); o.y = f2bf(od0[4 * s + 1] * inv);
            o.z = f2bf(od0[4 * s + 2] * inv); o.w = f2bf(od0[4 * s + 3] * inv);
            *(u16x4*)(cp + 8 * s + 4 * h) = o;
            o.x = f2bf(od1[4 * s + 0] * inv); o.y = f2bf(od1[4 * s + 1] * inv);
            o.z = f2bf(od1[4 * s + 2] * inv); o.w = f2bf(od1[4 * s + 3] * inv);
            *(u16x4*)(cp + 32 + 8 * s + 4 * h) = o;
        }
    }
}

// ---------------------------------------------------------------- out GEMM + bias + residual -> fp32
// R24: 512-thread / 8-wave 128x128 tile; 8 waves/CU doubles the latency-hiding pool vs 4-wave.
__global__ __launch_bounds__(512) void k_out(const u16* __restrict__ CTX, const u16* __restrict__ Wo,
                                             const float* __restrict__ bout, const float* __restrict__ X,
                                             float* __restrict__ OUT) {
    __shared__ __align__(16) u16 As[128 * 64], Bs[128 * 64];
    const int tid = threadIdx.x;
    const int lane = tid & 63;
    const int wv = tid >> 6;                       // 0..7
    const int qi = lane & 15, g = lane >> 4, swz = qi & 7;
    const int wr = (wv >> 1) * 32, wc = (wv & 1) * 64;
    const int m0 = blockIdx.y * 128, n0 = blockIdx.x * 128;

    f32x4 acc[2][4];
    #pragma unroll
    for (int mi = 0; mi < 2; mi++)
        #pragma unroll
        for (int ni = 0; ni < 4; ni++) acc[mi][ni] = (f32x4){0.f, 0.f, 0.f, 0.f};

    const int row_in = tid >> 3;                   // 0..63
    const int cs = (tid & 7) ^ (row_in & 7);       // swizzled source col-granule (i*64 preserves row&7)
    for (int k0 = 0; k0 < 1024; k0 += 64) {
        __syncthreads();
        #pragma unroll
        for (int i = 0; i < 2; i++) {
            int row = i * 64 + row_in;
            cp16(CTX + (size_t)(m0 + row) * 1024 + k0 + cs * 8, As + (i * 512 + wv * 64) * 8);
            cp16(Wo  + (size_t)(n0 + row) * 1024 + k0 + cs * 8, Bs + (i * 512 + wv * 64) * 8);
        }
        __syncthreads();
        #pragma unroll
        for (int ks = 0; ks < 2; ks++) {
            bf16x8 af[2], bf[4];
            #pragma unroll
            for (int mi = 0; mi < 2; mi++)
                af[mi] = *(const bf16x8*)(As + (wr + mi * 16 + qi) * 64 + ((ks * 4 + g) ^ swz) * 8);
            #pragma unroll
            for (int ni = 0; ni < 4; ni++)
                bf[ni] = *(const bf16x8*)(Bs + (wc + ni * 16 + qi) * 64 + ((ks * 4 + g) ^ swz) * 8);
            __builtin_amdgcn_s_setprio(1);
            #pragma unroll
            for (int mi = 0; mi < 2; mi++)
                #pragma unroll
                for (int ni = 0; ni < 4; ni++)
                    acc[mi][ni] = __builtin_amdgcn_mfma_f32_16x16x32_bf16(af[mi], bf[ni], acc[mi][ni], 0, 0, 0);
            __builtin_amdgcn_s_setprio(0);
        }
    }

    #pragma unroll
    for (int mi = 0; mi < 2; mi++)
        #pragma unroll
        for (int ni = 0; ni < 4; ni++)
            #pragma unroll
            for (int i = 0; i < 4; i++) {
                size_t m = m0 + wr + mi * 16 + (g * 4 + i);
                int n = n0 + wc + ni * 16 + qi;
                OUT[m * 1024 + n] = acc[mi][ni][i] + bout[n] + X[m * 1024 + n];
            }
}

// ---------------------------------------------------------------- launch
extern "C" void kernel_launch(void* const* d_in, const int* in_sizes, int n_in,
                              void* d_out, int out_size, void* d_ws, size_t ws_size,
                              hipStream_t stream) {
    const float* X    = (const float*)d_in[0];
    const float* gam  = (const float*)d_in[1];
    const float* bet  = (const float*)d_in[2];
    const float* Wqkv = (const float*)d_in[3];
    const float* bqkv = (const float*)d_in[4];
    const float* Wout = (const float*)d_in[5];
    const float* bout = (const float*)d_in[6];
    float* OUT = (float*)d_out;

    u16* XN  = (u16*)d_ws;
    u16* Q   = XN  + (size_t)4 * 1024 * 1024;
    u16* K   = Q   + (size_t)4 * 1024 * 1024;
    u16* Vt  = K   + (size_t)4 * 1024 * 1024;    // [bh,d,s] — written directly by k_qkv
    u16* CTX = Vt  + (size_t)4 * 1024 * 1024;
    u16* Wq  = CTX + (size_t)4 * 1024 * 1024;
    u16* Wo  = Wq  + (size_t)3 * 1024 * 1024;

    k_pre<<<8192, 256, 0, stream>>>(X, gam, bet, XN, Wqkv, Wq, Wout, Wo);
    k_qkv<<<192, 512, 0, stream>>>(XN, Wq, bqkv, Q, K, Vt);
    k_attn<<<512, 512, 0, stream>>>(Q, K, Vt, CTX);
    k_out<<<dim3(8, 32), 512, 0, stream>>>(CTX, Wo, bout, X, OUT);
}

// Round 11
// 182.021 us; speedup vs baseline: 1.0045x; 1.0045x over previous
//
#include <hip/hip_runtime.h>
#include <stdint.h>

typedef unsigned short u16;
typedef __attribute__((ext_vector_type(8))) short bf16x8;   // 8 bf16 = 4 VGPRs (MFMA A/B frag)
typedef __attribute__((ext_vector_type(4))) float f32x4;    // MFMA C/D frag
typedef __attribute__((ext_vector_type(4))) unsigned int u32x4;
typedef __attribute__((ext_vector_type(2))) unsigned int u32x2;
typedef __attribute__((ext_vector_type(4))) unsigned short u16x4;

#define QSCALE 0.18033688011112042f   // 0.125 * log2(e): softmax scale folded into Q, exp via exp2

typedef __attribute__((address_space(1))) const void gvoid;
typedef __attribute__((address_space(3))) void svoid;

__device__ __forceinline__ void cp16(const u16* g, u16* l) {
    // async global->LDS, 16B/lane; LDS dst = wave-uniform base + lane*16
    __builtin_amdgcn_global_load_lds((gvoid*)g, (svoid*)l, 16, 0, 0);
}

__device__ __forceinline__ u16 f2bf(float f) {
    uint32_t u = __float_as_uint(f);
    u += 0x7fff + ((u >> 16) & 1);   // round-to-nearest-even
    return (u16)(u >> 16);
}

// pack bf16(lo), bf16(hi) into one u32 via the HW packer (T12, RTNE) — 1 op per 2 elems
__device__ __forceinline__ uint32_t cvtpk_bf2(float lo, float hi) {
    uint32_t r;
    asm("v_cvt_pk_bf16_f32 %0, %1, %2" : "=v"(r) : "v"(lo), "v"(hi));
    return r;
}

// ---------------------------------------------------------------- fused pre-pass:
// blocks [0,4096): LayerNorm token t -> XN bf16; blocks [4096,8192): weight fp32->bf16 cast
__global__ __launch_bounds__(256) void k_pre(const float* __restrict__ X,
                                             const float* __restrict__ gam,
                                             const float* __restrict__ bet,
                                             u16* __restrict__ XN,
                                             const float* __restrict__ Wqkv, u16* __restrict__ Wq,
                                             const float* __restrict__ Wout, u16* __restrict__ Wo) {
    __shared__ float red[8];
    const int bid = blockIdx.x;
    if (bid < 4096) {
        int t = bid;
        const float4* xp = (const float4*)(X + (size_t)t * 1024);
        float4 x = xp[threadIdx.x];
        float s  = x.x + x.y + x.z + x.w;
        float s2 = x.x*x.x + x.y*x.y + x.z*x.z + x.w*x.w;
        #pragma unroll
        for (int off = 1; off < 64; off <<= 1) {
            s  += __shfl_xor(s,  off, 64);
            s2 += __shfl_xor(s2, off, 64);
        }
        int lane = threadIdx.x & 63, w = threadIdx.x >> 6;
        if (lane == 0) { red[w] = s; red[w + 4] = s2; }
        __syncthreads();
        s  = red[0] + red[1] + red[2] + red[3];
        s2 = red[4] + red[5] + red[6] + red[7];
        float mu  = s * (1.0f / 1024.0f);
        float var = s2 * (1.0f / 1024.0f) - mu * mu;
        float rin = rsqrtf(var + 1e-5f);
        float4 g = ((const float4*)gam)[threadIdx.x];
        float4 b = ((const float4*)bet)[threadIdx.x];
        u16x4 o;
        o.x = f2bf((x.x - mu) * rin * g.x + b.x);
        o.y = f2bf((x.y - mu) * rin * g.y + b.y);
        o.z = f2bf((x.z - mu) * rin * g.z + b.z);
        o.w = f2bf((x.w - mu) * rin * g.w + b.w);
        *(u16x4*)(XN + (size_t)t * 1024 + threadIdx.x * 4) = o;
    } else {
        int i = (bid - 4096) * 256 + threadIdx.x;      // over 1048576 float4s total
        const float* src; u16* dst;
        if (i < 786432) { src = Wqkv; dst = Wq; }
        else            { i -= 786432; src = Wout; dst = Wo; }
        float4 v = ((const float4*)src)[i];
        u16x4 o;
        o.x = f2bf(v.x); o.y = f2bf(v.y); o.z = f2bf(v.z); o.w = f2bf(v.w);
        ((u16x4*)dst)[i] = o;
    }
}

// ---------------------------------------------------------------- QKV GEMM: 256x256 tile, 8-phase
// T2(swizzle)+T3(8-phase)+T4(counted vmcnt, never 0 in steady state)+T5(setprio) per the verified
// 256^2 template. BK=64, 8 waves (2M x 4N), per-wave 128x64 output, acc[8][4] f32x4.

#define CFENCE asm volatile("" ::: "memory")
#define BARX() do { CFENCE; __builtin_amdgcn_s_barrier(); CFENCE; } while (0)
#define LGKM0() asm volatile("s_waitcnt lgkmcnt(0)" ::: "memory")
#define VM0() asm volatile("s_waitcnt vmcnt(0)" ::: "memory")

__global__ __launch_bounds__(512, 2) void k_qkv(const u16* __restrict__ XN, const u16* __restrict__ Wq,
                                                const float* __restrict__ bqkv,
                                                u16* __restrict__ Q, u16* __restrict__ K,
                                                u16* __restrict__ Vt) {
    __shared__ __align__(16) u16 SMEM[65536];      // 128 KiB; reused for V-transpose in epilogue
    const int tid = threadIdx.x;
    const int lane = tid & 63, w = tid >> 6;       // w in 0..7
    const int qi = lane & 15, g = lane >> 4, swz = qi & 7;
    const int wr = (w >> 2) * 128, wc = (w & 3) * 64;

    // bijective XCD swizzle: 192 blocks, 24/XCD -> each XCD owns 2 contiguous M-rows (A-panel L2 reuse)
    const int id = blockIdx.x;
    const int sw = (id & 7) * 24 + (id >> 3);
    const int n0 = (sw % 12) * 256;
    const int m0 = (sw / 12) * 256;

    // staging thread constants (all stage-region base rows are multiples of 8 -> same swizzle const)
    const int laneRow = lane >> 3, laneCg = lane & 7;
    const int cs = laneCg ^ laneRow;
    const int aw = (w & 3) * 8 + (w >> 2) * 128;   // A-chunk wave base row (add q*32)
    const u16* gA = XN + (size_t)(m0 + aw + laneRow) * 1024 + cs * 8;
    const u16* gB = Wq + (size_t)(n0 + w * 8 + laneRow) * 1024 + cs * 8;

#define SM_A(s) (SMEM + (s) * 32768)
#define SM_B(s) (SMEM + (s) * 32768 + 16384)
#define STAGE_A(tau, q, s) cp16(gA + (size_t)(q) * 32 * 1024 + (tau) * 64, SM_A(s) + ((q) * 32 + aw) * 64)
#define STAGE_B(tau, part, s)                                                                       \
    do { cp16(gB + (size_t)(part) * 128 * 1024 + (tau) * 64, SM_B(s) + ((part) * 128 + w * 8) * 64); \
         cp16(gB + (size_t)((part) * 128 + 64) * 1024 + (tau) * 64,                                  \
              SM_B(s) + ((part) * 128 + 64 + w * 8) * 64); } while (0)

    f32x4 acc[8][4];
    #pragma unroll
    for (int mi = 0; mi < 8; mi++)
        #pragma unroll
        for (int ni = 0; ni < 4; ni++) acc[mi][ni] = (f32x4){0.f, 0.f, 0.f, 0.f};
    bf16x8 bf[4][2];

    // prologue: tile0 fully (8 loads) + tile1 minus Aq2/Aq3 (6 loads); wait 8 oldest
    STAGE_B(0, 0, 0); STAGE_B(0, 1, 0);
    STAGE_A(0, 0, 0); STAGE_A(0, 1, 0); STAGE_A(0, 2, 0); STAGE_A(0, 3, 0);
    STAGE_B(1, 0, 1); STAGE_B(1, 1, 1);
    STAGE_A(1, 0, 1); STAGE_A(1, 1, 1);
    asm volatile("s_waitcnt vmcnt(6)" ::: "memory");
    BARX();

#define PHASE_A(q)                                                                                   \
    bf16x8 af[2][2];                                                                                 \
    _Pragma("unroll") for (int m2 = 0; m2 < 2; m2++)                                                 \
    _Pragma("unroll") for (int ks = 0; ks < 2; ks++)                                                 \
        af[m2][ks] = *(const bf16x8*)(as_ + (wr + ((q) * 2 + m2) * 16 + qi) * 64 + (((ks * 4 + g) ^ swz)) * 8);

#define DO_MFMA(q)                                                                                   \
    __builtin_amdgcn_s_setprio(1);                                                                   \
    _Pragma("unroll") for (int m2 = 0; m2 < 2; m2++)                                                 \
    _Pragma("unroll") for (int ni = 0; ni < 4; ni++) {                                               \
        acc[(q) * 2 + m2][ni] = __builtin_amdgcn_mfma_f32_16x16x32_bf16(af[m2][0], bf[ni][0], acc[(q) * 2 + m2][ni], 0, 0, 0); \
        acc[(q) * 2 + m2][ni] = __builtin_amdgcn_mfma_f32_16x16x32_bf16(af[m2][1], bf[ni][1], acc[(q) * 2 + m2][ni], 0, 0, 0); \
    }                                                                                                \
    __builtin_amdgcn_s_setprio(0);

    for (int t = 0; t < 16; t++) {
        const int s = t & 1;
        const u16* as_ = SM_A(s);
        const u16* bs_ = SM_B(s);
        {   // phase 0: B-frags (held all tile) + A quadrant 0
            PHASE_A(0)
            #pragma unroll
            for (int ni = 0; ni < 4; ni++)
                #pragma unroll
                for (int ks = 0; ks < 2; ks++)
                    bf[ni][ks] = *(const bf16x8*)(bs_ + (wc + ni * 16 + qi) * 64 + ((ks * 4 + g) ^ swz) * 8);
            if (t < 15) { STAGE_A(t + 1, 2, s ^ 1); STAGE_A(t + 1, 3, s ^ 1); }
            BARX(); LGKM0();
            DO_MFMA(0)
            BARX();
        }
        {   // phase 1
            PHASE_A(1)
            if (t < 14) STAGE_B(t + 2, 0, s);
            BARX(); LGKM0();
            DO_MFMA(1)
            BARX();
        }
        {   // phase 2
            PHASE_A(2)
            if (t < 14) STAGE_B(t + 2, 1, s);
            BARX(); LGKM0();
            DO_MFMA(2)
            BARX();
        }
        {   // phase 3: boundary wait — counted vmcnt, drain only at tail
            PHASE_A(3)
            if (t < 14) { STAGE_A(t + 2, 0, s); STAGE_A(t + 2, 1, s); }
            BARX(); LGKM0();
            DO_MFMA(3)
            if (t < 14) { asm volatile("s_waitcnt vmcnt(6)" ::: "memory"); }
            else        { asm volatile("s_waitcnt vmcnt(0)" ::: "memory"); }
            BARX();
        }
    }

    // ---- epilogue (final BARX above separates last LDS reads from reuse)
    if (n0 < 2048) {
        const int which = n0 >> 10;                // 0 = Q, 1 = K (block-uniform; 256-tiles don't straddle)
        u16* base = which ? K : Q;
        const float scale = which ? 1.0f : QSCALE;
        #pragma unroll
        for (int mi = 0; mi < 8; mi++)
            #pragma unroll
            for (int ni = 0; ni < 4; ni++)
                #pragma unroll
                for (int i = 0; i < 4; i++) {
                    int m = m0 + wr + mi * 16 + (g * 4 + i);
                    int n = n0 + wc + ni * 16 + qi;
                    float v = (acc[mi][ni][i] + bqkv[n]) * scale;
                    int b = m >> 11, ss = m & 2047;
                    int hh = (n >> 6) & 15, d = n & 63;
                    base[((size_t)(b * 16 + hh) * 2048 + ss) * 64 + d] = f2bf(v);
                }
    } else {
        u16* Tw = SMEM + w * 4352;                 // per-wave 64x68 (stride 68: 8B-aligned rows)
        const int head = (n0 + wc - 2048) >> 6;    // each wave owns exactly one head's 64 dims
        const int b = m0 >> 11;
        #pragma unroll
        for (int h = 0; h < 2; h++) {              // two 64-row m-halves of the wave's 128 rows
            #pragma unroll
            for (int mi2 = 0; mi2 < 4; mi2++)
                #pragma unroll
                for (int ni = 0; ni < 4; ni++) {
                    int mi = h * 4 + mi2;
                    int n = n0 + wc + ni * 16 + qi;
                    float bq = bqkv[n];
                    u16x4 pk;
                    pk.x = f2bf(acc[mi][ni][0] + bq);
                    pk.y = f2bf(acc[mi][ni][1] + bq);
                    pk.z = f2bf(acc[mi][ni][2] + bq);
                    pk.w = f2bf(acc[mi][ni][3] + bq);
                    *(u16x4*)(Tw + (ni * 16 + qi) * 68 + mi2 * 16 + g * 4) = pk;
                }
            int s0 = (m0 + wr + h * 64) & 2047;    // s within the batch
            u16* vrow = Vt + (size_t)(b * 16 + head) * 64 * 2048 + s0 + qi * 4;
            #pragma unroll
            for (int dd = 0; dd < 16; dd++) {
                int d = dd * 4 + g;
                u16x4 val = *(const u16x4*)(Tw + d * 68 + qi * 4);
                *(u16x4*)(vrow + (size_t)d * 2048) = val;
            }
        }
    }
#undef SM_A
#undef SM_B
#undef STAGE_A
#undef STAGE_B
#undef PHASE_A
#undef DO_MFMA
}

// ---------------------------------------------------------------- attention — R26: R23 core + 4-slot ring,
// barrier per 2 steps. R25's null (DS ops halved, time flat) + R16's null (latency resched) +
// R22's win (VALU cut) => the ~1400cy/step unaccounted cost is the per-step full-drain barrier
// lockstep (32 alignments of 16 waves). R26 halves barrier count: 4 K/V slots (64 KB, still
// 2 blocks/CU), window = 2 steps: { vmcnt(0) [cheap: loads ~2 steps old] ; s_barrier ; issue 4
// cp16 into the 2 slots all waves just finished ; 2 compute steps on literal slot indices }.
// Per-wave vmcnt(0)-before-barrier makes every wave's DMA visible to all after the barrier
// (counted-N would race: vmcnt is per-wave). Compute body byte-identical to R23.
__global__ __launch_bounds__(512) void k_attn(const u16* __restrict__ Q, const u16* __restrict__ K,
                                              const u16* __restrict__ Vt, u16* __restrict__ CTX) {
    __shared__ __align__(16) u16 KS[4][64 * 64];   // elem(key r, d c) at r*64 + ((c>>3)^(r&7))*8 + (c&7)
    __shared__ __align__(16) u16 VS[4][64 * 64];   // elem(d r, key c) same swizzle
    const int id = blockIdx.x;
    const int bh = (id & 7) * 4 + ((id >> 3) & 3); // id%8 constant per bh -> same XCD
    const int q0 = (id >> 5) * 128;
    const int lane = threadIdx.x & 63, w = threadIdx.x >> 6;   // w in 0..7
    const int g = lane >> 4, qi = lane & 15, swz = qi & 7;
    const u16* Qp = Q  + (size_t)bh * (2048 * 64);
    const u16* Kp = K  + (size_t)bh * (2048 * 64);
    const u16* Vp = Vt + (size_t)bh * (64 * 2048);

    // staging: 8 waves x 64 lanes x 16B = one full 64x64 bf16 tile per cp16
    const int r0 = w * 8 + (lane >> 3);            // tile row 0..63
    const int cs = (lane & 7) ^ (r0 & 7);          // swizzled col-granule
    const u16* kg0 = Kp + (size_t)r0 * 64 + cs * 8;
    const u16* vg0 = Vp + (size_t)r0 * 2048 + cs * 8;

    bf16x8 bq[2];
    {
        const u16* qb = Qp + (size_t)(q0 + w * 16 + qi) * 64 + g * 8;
        bq[0] = *(const bf16x8*)(qb);
        bq[1] = *(const bf16x8*)(qb + 32);
    }
    float lsumA = 0.f, lsumB = 0.f;
    f32x4 od[4];
    #pragma unroll
    for (int nt = 0; nt < 4; nt++) od[nt] = (f32x4){0.f, 0.f, 0.f, 0.f};

    const int grbase = 2 * (g & 1) + (g >> 1);     // V granule offset (add 4*ks)

    // prologue: tiles 0,1 -> slots 0,1
    cp16(kg0,        KS[0] + w * 512);
    cp16(vg0,        VS[0] + w * 512);
    cp16(kg0 + 4096, KS[1] + w * 512);
    cp16(vg0 + 64,   VS[1] + w * 512);

    // prefetch cursors: next tile to stage = 2
    const u16* kgp = kg0 + 2 * 4096;
    const u16* vgp = vg0 + 2 * 64;

#define ATTN_STEP(SLOT)                                                                           \
    {                                                                                             \
        const u16* ksp = KS[SLOT];                                                                \
        const u16* vsp = VS[SLOT];                                                                \
        f32x4 sv[4];                                                                              \
        _Pragma("unroll")                                                                         \
        for (int nt = 0; nt < 4; nt++) sv[nt] = (f32x4){0.f, 0.f, 0.f, 0.f};                      \
        __builtin_amdgcn_s_setprio(1);                                                            \
        _Pragma("unroll")                                                                         \
        for (int ks = 0; ks < 2; ks++)                                                            \
            _Pragma("unroll")                                                                     \
            for (int nt = 0; nt < 4; nt++) {                                                      \
                bf16x8 ak = *(const bf16x8*)(ksp + (nt * 16 + qi) * 64 + ((ks * 4 + g) ^ swz) * 8); \
                sv[nt] = __builtin_amdgcn_mfma_f32_16x16x32_bf16(ak, bq[ks], sv[nt], 0, 0, 0);    \
            }                                                                                     \
        __builtin_amdgcn_s_setprio(0);                                                            \
        _Pragma("unroll")                                                                         \
        for (int ks = 0; ks < 2; ks++) {                                                          \
            uint32_t p0[2], p1[2];                                                                \
            _Pragma("unroll")                                                                     \
            for (int j = 0; j < 2; j++) {                                                         \
                const int nt = 2 * ks + j;                                                        \
                float e0 = __builtin_amdgcn_exp2f(sv[nt][0]);                                     \
                float e1 = __builtin_amdgcn_exp2f(sv[nt][1]);                                     \
                float e2 = __builtin_amdgcn_exp2f(sv[nt][2]);                                     \
                float e3 = __builtin_amdgcn_exp2f(sv[nt][3]);                                     \
                lsumA += e0 + e1; lsumB += e2 + e3;                                               \
                p0[j] = cvtpk_bf2(e0, e1);                                                        \
                p1[j] = cvtpk_bf2(e2, e3);                                                        \
            }                                                                                     \
            u32x2 sA = __builtin_amdgcn_permlane16_swap(p0[0], p0[1], false, false);              \
            u32x2 sB = __builtin_amdgcn_permlane16_swap(p1[0], p1[1], false, false);              \
            u32x4 bw = {sA.x, sB.x, sA.y, sB.y};   /* k-slots g*8 + {0..7} */                     \
            bf16x8 bp = *(const bf16x8*)&bw;                                                      \
            const int gr = 4 * ks + grbase;        /* matching V granule */                       \
            __builtin_amdgcn_s_setprio(1);                                                        \
            _Pragma("unroll")                                                                     \
            for (int nt = 0; nt < 4; nt++) {                                                      \
                bf16x8 av = *(const bf16x8*)(vsp + (nt * 16 + qi) * 64 + (gr ^ swz) * 8);         \
                od[nt] = __builtin_amdgcn_mfma_f32_16x16x32_bf16(av, bp, od[nt], 0, 0, 0);        \
            }                                                                                     \
            __builtin_amdgcn_s_setprio(0);                                                        \
        }                                                                                         \
    }

    for (int kk = 0; kk < 8; ++kk) {
        // ---- window A: consume tiles 4kk,4kk+1 (slots 0,1); prefetch 4kk+2,4kk+3 -> slots 2,3
        VM0(); BARX();                             // own DMA drained -> after barrier ALL waves' tiles 4kk,4kk+1 visible
        cp16(kgp,        KS[2] + w * 512);         // slots 2,3: last read 2 steps ago by all waves (pre-barrier)
        cp16(vgp,        VS[2] + w * 512);
        cp16(kgp + 4096, KS[3] + w * 512);
        cp16(vgp + 64,   VS[3] + w * 512);
        kgp += 2 * 4096; vgp += 2 * 64;
        ATTN_STEP(0)
        ATTN_STEP(1)
        // ---- window B: consume tiles 4kk+2,4kk+3 (slots 2,3); prefetch 4kk+4,4kk+5 -> slots 0,1
        VM0(); BARX();
        if (kk < 7) {
            cp16(kgp,        KS[0] + w * 512);
            cp16(vgp,        VS[0] + w * 512);
            cp16(kgp + 4096, KS[1] + w * 512);
            cp16(vgp + 64,   VS[1] + w * 512);
            kgp += 2 * 4096; vgp += 2 * 64;
        }
        ATTN_STEP(2)
        ATTN_STEP(3)
    }
#undef ATTN_STEP

    float lsum = lsumA + lsumB;
    lsum += __shfl_xor(lsum, 16, 64);
    lsum += __shfl_xor(lsum, 32, 64);
    float inv = 1.0f / lsum;
    const int b = bh >> 4, hh = bh & 15;
    size_t m = (size_t)b * 2048 + q0 + w * 16 + qi;
    u16* cp = CTX + m * 1024 + hh * 64 + g * 4;
    #pragma unroll
    for (int nt = 0; nt < 4; nt++) {
        u16x4 o;
        o.x = f2bf(od[nt][0] * inv); o.y = f2bf(od[nt][1] * inv);
        o.z = f2bf(od[nt][2] * inv); o.w = f2bf(od[nt][3] * inv);
        *(u16x4*)(cp + nt * 16) = o;
    }
}

// ---------------------------------------------------------------- out GEMM + bias + residual -> fp32
// R24: 512-thread / 8-wave 128x128 tile; 8 waves/CU doubles the latency-hiding pool vs 4-wave.
__global__ __launch_bounds__(512) void k_out(const u16* __restrict__ CTX, const u16* __restrict__ Wo,
                                             const float* __restrict__ bout, const float* __restrict__ X,
                                             float* __restrict__ OUT) {
    __shared__ __align__(16) u16 As[128 * 64], Bs[128 * 64];
    const int tid = threadIdx.x;
    const int lane = tid & 63;
    const int wv = tid >> 6;                       // 0..7
    const int qi = lane & 15, g = lane >> 4, swz = qi & 7;
    const int wr = (wv >> 1) * 32, wc = (wv & 1) * 64;
    const int m0 = blockIdx.y * 128, n0 = blockIdx.x * 128;

    f32x4 acc[2][4];
    #pragma unroll
    for (int mi = 0; mi < 2; mi++)
        #pragma unroll
        for (int ni = 0; ni < 4; ni++) acc[mi][ni] = (f32x4){0.f, 0.f, 0.f, 0.f};

    const int row_in = tid >> 3;                   // 0..63
    const int cs = (tid & 7) ^ (row_in & 7);       // swizzled source col-granule (i*64 preserves row&7)
    for (int k0 = 0; k0 < 1024; k0 += 64) {
        __syncthreads();
        #pragma unroll
        for (int i = 0; i < 2; i++) {
            int row = i * 64 + row_in;
            cp16(CTX + (size_t)(m0 + row) * 1024 + k0 + cs * 8, As + (i * 512 + wv * 64) * 8);
            cp16(Wo  + (size_t)(n0 + row) * 1024 + k0 + cs * 8, Bs + (i * 512 + wv * 64) * 8);
        }
        __syncthreads();
        #pragma unroll
        for (int ks = 0; ks < 2; ks++) {
            bf16x8 af[2], bf[4];
            #pragma unroll
            for (int mi = 0; mi < 2; mi++)
                af[mi] = *(const bf16x8*)(As + (wr + mi * 16 + qi) * 64 + ((ks * 4 + g) ^ swz) * 8);
            #pragma unroll
            for (int ni = 0; ni < 4; ni++)
                bf[ni] = *(const bf16x8*)(Bs + (wc + ni * 16 + qi) * 64 + ((ks * 4 + g) ^ swz) * 8);
            __builtin_amdgcn_s_setprio(1);
            #pragma unroll
            for (int mi = 0; mi < 2; mi++)
                #pragma unroll
                for (int ni = 0; ni < 4; ni++)
                    acc[mi][ni] = __builtin_amdgcn_mfma_f32_16x16x32_bf16(af[mi], bf[ni], acc[mi][ni], 0, 0, 0);
            __builtin_amdgcn_s_setprio(0);
        }
    }

    #pragma unroll
    for (int mi = 0; mi < 2; mi++)
        #pragma unroll
        for (int ni = 0; ni < 4; ni++)
            #pragma unroll
            for (int i = 0; i < 4; i++) {
                size_t m = m0 + wr + mi * 16 + (g * 4 + i);
                int n = n0 + wc + ni * 16 + qi;
                OUT[m * 1024 + n] = acc[mi][ni][i] + bout[n] + X[m * 1024 + n];
            }
}

// ---------------------------------------------------------------- launch
extern "C" void kernel_launch(void* const* d_in, const int* in_sizes, int n_in,
                              void* d_out, int out_size, void* d_ws, size_t ws_size,
                              hipStream_t stream) {
    const float* X    = (const float*)d_in[0];
    const float* gam  = (const float*)d_in[1];
    const float* bet  = (const float*)d_in[2];
    const float* Wqkv = (const float*)d_in[3];
    const float* bqkv = (const float*)d_in[4];
    const float* Wout = (const float*)d_in[5];
    const float* bout = (const float*)d_in[6];
    float* OUT = (float*)d_out;

    u16* XN  = (u16*)d_ws;
    u16* Q   = XN  + (size_t)4 * 1024 * 1024;
    u16* K   = Q   + (size_t)4 * 1024 * 1024;
    u16* Vt  = K   + (size_t)4 * 1024 * 1024;    // [bh,d,s] — written directly by k_qkv
    u16* CTX = Vt  + (size_t)4 * 1024 * 1024;
    u16* Wq  = CTX + (size_t)4 * 1024 * 1024;
    u16* Wo  = Wq  + (size_t)3 * 1024 * 1024;

    k_pre<<<8192, 256, 0, stream>>>(X, gam, bet, XN, Wqkv, Wq, Wout, Wo);
    k_qkv<<<192, 512, 0, stream>>>(XN, Wq, bqkv, Q, K, Vt);
    k_attn<<<512, 512, 0, stream>>>(Q, K, Vt, CTX);
    k_out<<<dim3(8, 32), 512, 0, stream>>>(CTX, Wo, bout, X, OUT);
}